// Round 8
// baseline (602.084 us; speedup 1.0000x reference)
//
#include <hip/hip_runtime.h>
#include <hip/hip_cooperative_groups.h>
#include <cstdint>

namespace cg = cooperative_groups;

// Problem constants (from the reference)
#define LL    200
#define QQ    21
#define MM    1024
#define START 133        // 2*L//3
#define NS    67         // L - START
#define RGH   0.01f
#define RGJ   0.01f

// ws layout:
//   [0, 1024)              : acc slots (3 x 64 fp32) + steal counter (int @768)
//   [1024, +LL*MM*4)       : tokT (transposed tokens, [j][n])
//   [TOKT end, +SLAB)      : partial-logits slab [y][iIdx][a][n]
#define SLOT_J2  0
#define SLOT_E   64
#define SLOT_LZ  128
#define CTR_OFF  192      // float index of the int work-steal counter
#define TOKT_OFF 1024
#define TOKT_BYTES ((size_t)LL * MM * 4)
#define SLAB_OFF (TOKT_OFF + TOKT_BYTES)
#define SLAB_BYTES ((size_t)2 * NS * QQ * MM * 4)
#define WS_FULL (SLAB_OFF + SLAB_BYTES)
#define WS_TOK  SLAB_OFF

// LDS tile: raw a-major copy of J[i, a, j0:j0+10, :]. Plane = 210 floats
// padded to 212 (16B-aligned plane stride for the 16B DMA writes).
// Gather tile[a*212 + jl*21 + b]: lanes differ only in b -> consecutive
// dwords -> conflict-free (R6/R7: SQ_LDS_BANK_CONFLICT == 0).
#define TJ 10
#define PLANE 212
#define TILE_FLOATS (QQ * PLANE)       // 4452 floats, 17808 B; x2 = 35616 B -> 4 blocks/CU

// Work units: 536 p1 units first (long), then 1024 fine jsum units.
#define NP1  (NS * 8)                  // 536
#define NJS  1024
#define NTOT (NP1 + NJS)
#define TOTAL4 (LL * QQ * LL * QQ / 4) // 4,410,000 float4 in J
#define CHUNK4 ((TOTAL4 + NJS - 1) / NJS)

typedef const uint32_t __attribute__((address_space(1)))* gq_t;
typedef uint32_t __attribute__((address_space(3)))* lq_t;

__device__ __forceinline__ float block_reduce_sum_256(float v) {
  __shared__ float sm[4];
  #pragma unroll
  for (int off = 32; off > 0; off >>= 1) v += __shfl_down(v, off, 64);
  const int lane = threadIdx.x & 63;
  const int wv   = threadIdx.x >> 6;
  __syncthreads();
  if (lane == 0) sm[wv] = v;
  __syncthreads();
  float r = 0.0f;
  if (threadIdx.x == 0) r = sm[0] + sm[1] + sm[2] + sm[3];
  return r;  // valid in thread 0 only
}

// ---------------------------------------------------------------------------
// DMA one tile (21 a-planes) into LDS; <=3-float overread stays inside row a
// of slice i (max offset j0*21 + rem*21 + 2 <= 199*21 + 2 < 4200).
// ---------------------------------------------------------------------------
__device__ __forceinline__ void dma_tile(
    const float* __restrict__ Ji, int j0, int rem, int wv, int lane,
    float* __restrict__ tile) {
  const int nlanes = (rem * QQ + 3) >> 2;
  if (lane < nlanes) {
    for (int a = wv; a < QQ; a += 4) {
      const float* g = Ji + a * (LL * QQ) + j0 * QQ + lane * 4;
      __builtin_amdgcn_global_load_lds((gq_t)g, (lq_t)(tile + a * PLANE),
                                       16, 0, 0);
    }
  }
}

__device__ __forceinline__ void tok_load(
    const int* __restrict__ tokT, int j0, int jend, int n, int (&bo)[TJ]) {
  #pragma unroll
  for (int k = 0; k < TJ; ++k) {
    if (j0 + k < jend) bo[k] = k * QQ + tokT[(j0 + k) * MM + n];
  }
}

__device__ __forceinline__ void gather_tile(
    const float* __restrict__ tile, const int (&bo)[TJ], int rem,
    float (&lg)[QQ]) {
  #pragma unroll
  for (int jl = 0; jl < TJ; ++jl) {
    if (jl >= rem) break;              // block-uniform
    const float* p = tile + bo[jl];
    #pragma unroll
    for (int a = 0; a < QQ; ++a) lg[a] += p[a * PLANE];
  }
}

// ---------------------------------------------------------------------------
// p1 unit: (site iI, j-half y, 256-seq chunk z). Double-buffered DMA,
// partial logits -> plain coalesced stores to the (y,iI) slab region.
// ---------------------------------------------------------------------------
__device__ void p1_unit(
    const float* __restrict__ J, const int* __restrict__ tokT,
    float* __restrict__ slab, int iI, int y, int z,
    float (*lds)[TILE_FLOATS]) {
  const int i  = START + iI;
  const int h0 = i >> 1;
  const int jbeg = y ? h0 : 0;
  const int jend = y ? i : h0;
  const int t = threadIdx.x, lane = t & 63, wv = t >> 6;
  const int n = z * 256 + t;
  const float* Ji = J + (size_t)i * (QQ * LL * QQ);
  const int ntiles = (jend - jbeg + TJ - 1) / TJ;

  float lg[QQ];
  #pragma unroll
  for (int a = 0; a < QQ; ++a) lg[a] = 0.0f;
  int boc[TJ], bon[TJ];

  dma_tile(Ji, jbeg, min(TJ, jend - jbeg), wv, lane, lds[0]);
  tok_load(tokT, jbeg, jend, n, boc);
  __syncthreads();                     // drains DMA(0)

  for (int s = 0; s < ntiles; ++s) {
    const int j0  = jbeg + s * TJ;
    const int rem = min(TJ, jend - j0);
    const bool more = (s + 1 < ntiles);
    if (more) {
      const int j1 = j0 + TJ;
      dma_tile(Ji, j1, min(TJ, jend - j1), wv, lane, lds[(s + 1) & 1]);
      tok_load(tokT, j1, jend, n, bon);
    }
    gather_tile(lds[s & 1], boc, rem, lg);   // overlaps in-flight DMA
    if (more) {
      #pragma unroll
      for (int k = 0; k < TJ; ++k) boc[k] = bon[k];
    }
    __syncthreads();
  }

  float* dst = slab + (((size_t)y * NS + iI) * QQ) * MM + n;
  #pragma unroll
  for (int a = 0; a < QQ; ++a) dst[a * MM] = lg[a];
}

// ---------------------------------------------------------------------------
// jsum fine unit v in [0,1024): a CHUNK4 slice of the J^2 stream + prefix
// rows r = v, v+1024 of the masked J*fij sum.
// ---------------------------------------------------------------------------
__device__ void jsum_unit(
    const float* __restrict__ J, const float* __restrict__ fij,
    float* __restrict__ acc, int v) {
  const int t = threadIdx.x;
  const float4* __restrict__ J4 = (const float4*)J;
  float j2 = 0.0f;
  const int beg = v * CHUNK4;
  const int end = min(beg + CHUNK4, TOTAL4);
  for (int f = beg + t; f < end; f += 256) {
    const float4 q = J4[f];
    j2 += q.x * q.x + q.y * q.y + q.z * q.z + q.w * q.w;
  }
  float e = 0.0f;
  for (int r = v; r < NS * QQ; r += NJS) {
    const int iI = r / QQ;
    const int a  = r - iI * QQ;
    const int i  = START + iI;
    const size_t base = (size_t)i * (QQ * LL * QQ) + (size_t)a * (LL * QQ);
    const float4* __restrict__ Jb = (const float4*)(J + base);
    const float4* __restrict__ Fb = (const float4*)(fij + base);
    const int lim  = i * QQ;
    const int lim4 = lim >> 2;
    for (int f = t; f < lim4; f += 256) {
      const float4 q = Jb[f], u = Fb[f];
      e += q.x * u.x + q.y * u.y + q.z * u.z + q.w * u.w;
    }
    const int rem = lim & 3;
    if (t < rem) {
      const int p = lim4 * 4 + t;
      e += (J + base)[p] * (fij + base)[p];
    }
  }
  const float tj2 = block_reduce_sum_256(j2);
  const float te  = block_reduce_sum_256(e);
  if (t == 0) {
    atomicAdd(acc + SLOT_J2 + (v & 63), tj2);
    atomicAdd(acc + SLOT_E  + (v & 63), te);
  }
}

// ---------------------------------------------------------------------------
// p2 unit: combine j-half partials for (iI, 256-chunk z), logsumexp, weighted.
// ---------------------------------------------------------------------------
__device__ void p2_unit(
    const float* __restrict__ slab, const float* __restrict__ h,
    const float* __restrict__ w, float* __restrict__ acc, int iI, int z) {
  const int t = threadIdx.x;
  const int n = z * 256 + t;
  const float* s0 = slab + ((size_t)iI * QQ) * MM + n;
  const float* s1 = slab + (((size_t)NS + iI) * QQ) * MM + n;
  const float* hi = h + (START + iI) * QQ;
  float lg[QQ];
  float mx = -3.0e38f;
  #pragma unroll
  for (int a = 0; a < QQ; ++a) {
    lg[a] = s0[a * MM] + s1[a * MM] + hi[a];
    mx = fmaxf(mx, lg[a]);
  }
  float sme = 0.0f;
  #pragma unroll
  for (int a = 0; a < QQ; ++a) sme += expf(lg[a] - mx);
  const float contrib = w[n] * (mx + logf(sme));
  const float tot = block_reduce_sum_256(contrib);
  if (t == 0) atomicAdd(acc + SLOT_LZ + (iI & 63), tot);
}

// ---------------------------------------------------------------------------
// final body: slot sums + h-side terms + weight normalization.
// ---------------------------------------------------------------------------
__device__ void final_body(
    const float* __restrict__ h, const float* __restrict__ fi,
    const float* __restrict__ w, const float* __restrict__ acc,
    float* __restrict__ out) {
  const int t = threadIdx.x;
  const float sj2 = block_reduce_sum_256(t < 64 ? acc[SLOT_J2 + t] : 0.0f);
  const float se  = block_reduce_sum_256(t < 64 ? acc[SLOT_E + t] : 0.0f);
  const float slz = block_reduce_sum_256(t < 64 ? acc[SLOT_LZ + t] : 0.0f);
  float hs = 0.0f, eh = 0.0f, ws = 0.0f;
  for (int idx = t; idx < LL * QQ; idx += 256) {
    const float hv = h[idx];
    hs += hv * hv;
    if (idx >= START * QQ) eh += fi[idx] * hv;
  }
  for (int idx = t; idx < MM; idx += 256) ws += w[idx];
  const float ths = block_reduce_sum_256(hs);
  const float teh = block_reduce_sum_256(eh);
  const float tws = block_reduce_sum_256(ws);
  if (t == 0) {
    const float energy = teh + se;
    const float nll = slz / tws - energy;
    out[0] = nll + RGH * ths + RGJ * sj2;
    out[1] = nll;
  }
}

// ---------------------------------------------------------------------------
// Cooperative whole-pipeline kernel. P0 init+tokT / P1 work-steal over
// p1+jsum units / P2 logsumexp / P3 final. One graph node replaces five.
// ---------------------------------------------------------------------------
__global__ __launch_bounds__(256) void kern_coop(
    const int* __restrict__ Xtok, const float* __restrict__ wts,
    const float* __restrict__ fi, const float* __restrict__ fij,
    const float* __restrict__ h, const float* __restrict__ J,
    float* __restrict__ acc, int* __restrict__ tokT,
    float* __restrict__ slab, float* __restrict__ out) {
  __shared__ float lds[2][TILE_FLOATS];
  __shared__ int s_unit;
  cg::grid_group grid = cg::this_grid();
  const int t = threadIdx.x;
  const int nb = gridDim.x;

  // P0: zero acc slots + steal counter; build tokT (MM=1024 -> shifts).
  if (blockIdx.x == 0) acc[t] = 0.0f;          // 256 floats = slots + ctr
  for (int idx = blockIdx.x * 256 + t; idx < LL * MM; idx += nb * 256) {
    const int j = idx >> 10;
    const int n = idx & (MM - 1);
    tokT[idx] = Xtok[n * LL + j];
  }
  __threadfence();
  grid.sync();

  // P1: self-balancing work-steal; p1 units (big sites first) then jsum.
  int* ctr = (int*)(acc + CTR_OFF);
  for (;;) {
    __syncthreads();                           // protect s_unit reuse
    if (t == 0) s_unit = atomicAdd(ctr, 1);
    __syncthreads();
    const int u = s_unit;
    if (u >= NTOT) break;
    if (u < NP1) {
      const int s    = u % NS;
      const int rest = u / NS;                 // 0..7
      p1_unit(J, tokT, slab, NS - 1 - s, rest & 1, rest >> 1, lds);
    } else {
      jsum_unit(J, fij, acc, u - NP1);
    }
  }
  __threadfence();
  grid.sync();

  // P2: 268 units (iI, z), grid-stride.
  for (int u = blockIdx.x; u < NS * 4; u += nb) {
    p2_unit(slab, h, wts, acc, u >> 2, u & 3);
  }
  __threadfence();
  grid.sync();

  // P3
  if (blockIdx.x == 0) final_body(h, fi, wts, acc, out);
}

// ---------------------------------------------------------------------------
// Fallback multi-kernel path (if cooperative launch is unavailable).
// ---------------------------------------------------------------------------
__global__ __launch_bounds__(256) void kern_tokT(
    const int* __restrict__ X, int* __restrict__ tokT) {
  const int idx = blockIdx.x * 256 + threadIdx.x;
  if (idx < LL * MM) tokT[idx] = X[(idx & (MM - 1)) * LL + (idx >> 10)];
}

__global__ __launch_bounds__(256) void kern_mega(
    const float* __restrict__ J, const float* __restrict__ fij,
    const int* __restrict__ tokT, float* __restrict__ slab,
    float* __restrict__ acc) {
  __shared__ float lds[2][TILE_FLOATS];
  const int bx = blockIdx.x;
  if (bx < NP1) {
    const int s    = bx % NS;
    const int rest = bx / NS;
    p1_unit(J, tokT, slab, NS - 1 - s, rest & 1, rest >> 1, lds);
  } else {
    jsum_unit(J, fij, acc, bx - NP1);
  }
}

__global__ __launch_bounds__(256) void kern_logz_p2(
    const float* __restrict__ slab, const float* __restrict__ h,
    const float* __restrict__ w, float* __restrict__ acc) {
  p2_unit(slab, h, w, acc, blockIdx.x, blockIdx.y);
}

__global__ __launch_bounds__(256) void kern_final(
    const float* __restrict__ h, const float* __restrict__ fi,
    const float* __restrict__ w, const float* __restrict__ acc,
    float* __restrict__ out) {
  final_body(h, fi, w, acc, out);
}

// Mono fallback for tiny ws: all j in block + logsumexp epilogue.
__global__ __launch_bounds__(256) void kern_logz_mono(
    const float* __restrict__ J, const int* __restrict__ Xtok,
    const float* __restrict__ h, const float* __restrict__ w,
    float* __restrict__ acc) {
  __shared__ float lds[2][TILE_FLOATS];
  const int i = START + blockIdx.x;
  const int t = threadIdx.x, lane = t & 63, wv = t >> 6;
  const int n = blockIdx.z * 256 + t;
  const float* Ji = J + (size_t)i * (QQ * LL * QQ);
  const int ntiles = (i + TJ - 1) / TJ;
  float lg[QQ];
  #pragma unroll
  for (int a = 0; a < QQ; ++a) lg[a] = 0.0f;
  int boc[TJ];
  dma_tile(Ji, 0, min(TJ, i), wv, lane, lds[0]);
  __syncthreads();
  for (int s = 0; s < ntiles; ++s) {
    const int j0  = s * TJ;
    const int rem = min(TJ, i - j0);
    #pragma unroll
    for (int k = 0; k < TJ; ++k)
      if (k < rem) boc[k] = k * QQ + Xtok[n * LL + (j0 + k)];
    if (s + 1 < ntiles) {
      const int j1 = j0 + TJ;
      dma_tile(Ji, j1, min(TJ, i - j1), wv, lane, lds[(s + 1) & 1]);
    }
    gather_tile(lds[s & 1], boc, rem, lg);
    __syncthreads();
  }
  const float* hi = h + i * QQ;
  float mx = -3.0e38f;
  #pragma unroll
  for (int a = 0; a < QQ; ++a) { lg[a] += hi[a]; mx = fmaxf(mx, lg[a]); }
  float sme = 0.0f;
  #pragma unroll
  for (int a = 0; a < QQ; ++a) sme += expf(lg[a] - mx);
  const float contrib = w[n] * (mx + logf(sme));
  const float tot = block_reduce_sum_256(contrib);
  if (t == 0) atomicAdd(acc + SLOT_LZ + (blockIdx.x & 63), tot);
}

__global__ __launch_bounds__(256) void kern_jsum_only(
    const float* __restrict__ J, const float* __restrict__ fij,
    float* __restrict__ acc) {
  jsum_unit(J, fij, acc, blockIdx.x);
}

extern "C" void kernel_launch(void* const* d_in, const int* in_sizes, int n_in,
                              void* d_out, int out_size, void* d_ws, size_t ws_size,
                              hipStream_t stream) {
  const int*   Xtok = (const int*)  d_in[0];
  const float* wts  = (const float*)d_in[1];
  const float* fi   = (const float*)d_in[2];
  const float* fij  = (const float*)d_in[3];
  const float* h    = (const float*)d_in[4];
  const float* J    = (const float*)d_in[5];
  float* out  = (float*)d_out;
  float* acc  = (float*)d_ws;
  int*   tokT = (int*)((char*)d_ws + TOKT_OFF);
  float* slab = (float*)((char*)d_ws + SLAB_OFF);

  if (ws_size >= WS_FULL) {
    int perCU = 0;
    hipError_t qe = hipOccupancyMaxActiveBlocksPerMultiprocessor(
        &perCU, (const void*)kern_coop, 256, 0);
    int grid = (qe == hipSuccess && perCU > 0) ? perCU * 256 : 512;
    if (grid > 1024) grid = 1024;
    void* args[] = {(void*)&Xtok, (void*)&wts, (void*)&fi, (void*)&fij,
                    (void*)&h,    (void*)&J,   (void*)&acc, (void*)&tokT,
                    (void*)&slab, (void*)&out};
    hipError_t le = hipLaunchCooperativeKernel(
        (const void*)kern_coop, dim3(grid), dim3(256), args, 0, stream);
    if (le == hipSuccess) return;
    // fall through to multi-kernel path
    hipMemsetAsync(d_ws, 0, 1024, stream);
    kern_tokT<<<(LL * MM + 255) / 256, 256, 0, stream>>>(Xtok, tokT);
    kern_mega<<<NP1 + NJS, 256, 0, stream>>>(J, fij, tokT, slab, acc);
    kern_logz_p2<<<dim3(NS, 4), 256, 0, stream>>>(slab, h, wts, acc);
    kern_final<<<1, 256, 0, stream>>>(h, fi, wts, acc, out);
  } else {
    hipMemsetAsync(d_ws, 0, 1024, stream);
    kern_jsum_only<<<NJS, 256, 0, stream>>>(J, fij, acc);
    kern_logz_mono<<<dim3(NS, 1, 4), 256, 0, stream>>>(J, Xtok, h, wts, acc);
    kern_final<<<1, 256, 0, stream>>>(h, fi, wts, acc, out);
  }
}